// Round 8
// baseline (261.235 us; speedup 1.0000x reference)
//
#include <hip/hip_runtime.h>

typedef __bf16 bf16;
typedef __bf16 bf16x4 __attribute__((ext_vector_type(4)));
typedef __bf16 bf16x8 __attribute__((ext_vector_type(8)));
typedef short s16x4 __attribute__((ext_vector_type(4)));
typedef float f32x4 __attribute__((ext_vector_type(4)));
typedef unsigned int u32x4 __attribute__((ext_vector_type(4)));

#define NB 2
#define NT 2048
#define NC 1024
#define NH 16
#define ND 64

#if __has_builtin(__builtin_amdgcn_exp2f)
#define EXP2F(x) __builtin_amdgcn_exp2f(x)
#else
#define EXP2F(x) __expf(0.69314718055994531f * (x))
#endif

#if __has_builtin(__builtin_amdgcn_rcpf)
#define RCPF(x) __builtin_amdgcn_rcpf(x)
#else
#define RCPF(x) (1.0f / (x))
#endif

__device__ __forceinline__ void async16(const void* g, void* l) {
  __builtin_amdgcn_global_load_lds(
      (const __attribute__((address_space(1))) void*)g,
      (__attribute__((address_space(3))) void*)l, 16, 0, 0);
}

__device__ __forceinline__ bf16x8 ld8(const bf16* p) {
  return *reinterpret_cast<const bf16x8*>(p);
}
__device__ __forceinline__ bf16x4 ld4(const bf16* p) {
  return *reinterpret_cast<const bf16x4*>(p);
}

// 16x16x16 bf16 MFMA: A-frag layout == 16x16 C-layout, so P^T feeds B directly
__device__ __forceinline__ f32x4 mfma16(bf16x4 a, bf16x4 b, f32x4 c) {
  s16x4 ai = __builtin_bit_cast(s16x4, a);
  s16x4 bi = __builtin_bit_cast(s16x4, b);
#if __has_builtin(__builtin_amdgcn_mfma_f32_16x16x16bf16_1k)
  return __builtin_amdgcn_mfma_f32_16x16x16bf16_1k(ai, bi, c, 0, 0, 0);
#else
  f32x4 d;
  asm("v_mfma_f32_16x16x16_bf16 %0, %1, %2, %3"
      : "=v"(d) : "v"(ai), "v"(bi), "v"(c));
  return d;
#endif
}

// ---------------- prep: x->bf16 cvt + both weight transposes, one launch ----------------
__global__ __launch_bounds__(256) void prep(
    const float* __restrict__ x, bf16* __restrict__ xb,
    const float* __restrict__ Wa, bf16* __restrict__ Da,
    const float* __restrict__ Wp, bf16* __restrict__ Dp) {
  int bx = blockIdx.x;
  if (bx < 2048) {
    int i = (bx * 256 + threadIdx.x) * 8;
    const float4* s = (const float4*)(x + i);
    float4 a = s[0], b = s[1];
    bf16x8 o;
    o[0] = (bf16)a.x; o[1] = (bf16)a.y; o[2] = (bf16)a.z; o[3] = (bf16)a.w;
    o[4] = (bf16)b.x; o[5] = (bf16)b.y; o[6] = (bf16)b.z; o[7] = (bf16)b.w;
    *(bf16x8*)(xb + i) = o;
    return;
  }
  __shared__ float tile[32][33];
  int idx = bx - 2048;
  const float* src;
  bf16* dst;
  int Cc, cb, rb;
  if (idx < 96 * 32) { src = Wa; dst = Da; Cc = 3072; cb = idx % 96; rb = idx / 96; }
  else { idx -= 96 * 32; src = Wp; dst = Dp; Cc = 1024; cb = idx % 32; rb = idx / 32; }
  int tx = threadIdx.x & 31, ty = threadIdx.x >> 5;
  int r0 = rb * 32, c0 = cb * 32;
#pragma unroll
  for (int i = 0; i < 4; ++i)
    tile[ty + i * 8][tx] = src[(size_t)(r0 + ty + i * 8) * Cc + c0 + tx];
  __syncthreads();
#pragma unroll
  for (int i = 0; i < 4; ++i)
    dst[(size_t)(c0 + ty + i * 8) * 1024 + r0 + tx] = (bf16)tile[tx][ty + i * 8];
}

// ---------------- QKV GEMM: [4096,1024] x [3072,1024]^T (r1 structure) ----------------
// 128^2 tiles, 768 blocks = 3/CU. 8-phase 256^2 template REGRESSED here (r2):
// only 192 tiles of 256^2 -> 0.75 blocks/CU coverage on this shape.
__global__ __launch_bounds__(256, 3) void gemm_qkv(
    const bf16* __restrict__ A,    // [4096][1024]
    const bf16* __restrict__ Bt,   // [3072][1024]  (W_attn^T)
    const float* __restrict__ bias,// [3072]
    bf16* __restrict__ Qo, bf16* __restrict__ Ko, bf16* __restrict__ Vto) {
  const int K = 1024;
  __shared__ bf16 As[128 * 32];
  __shared__ bf16 Bs[128 * 32];
  const int tid = threadIdx.x;
  const int lane = tid & 63, wv = tid >> 6;
  const int quad = lane >> 4, ln = lane & 15;
  const int m0 = blockIdx.x * 128, n0 = blockIdx.y * 128;
  const int wr = (wv >> 1) * 64, wc = (wv & 1) * 64;
  const int rA = tid >> 2, cA = (tid & 3) * 8;
  f32x4 acc[4][4] = {};

  for (int kt = 0; kt < K / 32; ++kt) {
    const int k0 = kt * 32;
#pragma unroll
    for (int inst = 0; inst < 2; ++inst) {
      async16(A + (size_t)(m0 + inst * 64 + rA) * K + k0 + cA,
              &As[inst * 2048 + wv * 512]);
      async16(Bt + (size_t)(n0 + inst * 64 + rA) * K + k0 + cA,
              &Bs[inst * 2048 + wv * 512]);
    }
    __syncthreads();
    bf16x8 aF[4], bF[4];
#pragma unroll
    for (int i = 0; i < 4; ++i) {
      aF[i] = ld8(&As[(wr + i * 16 + ln) * 32 + quad * 8]);
      bF[i] = ld8(&Bs[(wc + i * 16 + ln) * 32 + quad * 8]);
    }
#pragma unroll
    for (int rb = 0; rb < 4; ++rb)
#pragma unroll
      for (int cb = 0; cb < 4; ++cb)
        acc[rb][cb] = __builtin_amdgcn_mfma_f32_16x16x32_bf16(
            aF[rb], bF[cb], acc[rb][cb], 0, 0, 0);
    __syncthreads();
  }
  // epilogue: fold (1/8)*log2(e) into Q (exp2-domain softmax)
#pragma unroll
  for (int rb = 0; rb < 4; ++rb) {
#pragma unroll
    for (int cb = 0; cb < 4; ++cb) {
      int gn = n0 + wc + cb * 16 + ln;
      int part = gn >> 10, c = gn & 1023;
      int h = c >> 6, dd = c & 63;
      float bs = bias[gn];
      int gm0 = m0 + wr + rb * 16 + quad * 4;  // 4 consecutive rows
      int b = gm0 >> 11, t0 = gm0 & 2047;
      if (part == 2) {
        bf16x4 vv;
#pragma unroll
        for (int r = 0; r < 4; ++r) vv[r] = (bf16)(acc[rb][cb][r] + bs);
        *(bf16x4*)(Vto + ((size_t)(b * NH + h) * ND + dd) * NT + t0) = vv;
      } else {
        bf16* dst = part == 0 ? Qo : Ko;
        float sc = part == 0 ? 0.18033688f : 1.0f;  // 0.125 * log2(e)
#pragma unroll
        for (int r = 0; r < 4; ++r)
          dst[((size_t)(b * NH + h) * NT + t0 + r) * ND + dd] =
              (bf16)((acc[rb][cb][r] + bs) * sc);
      }
    }
  }
}

// ---------------- flash attention: LDS-free, direct-L2 streaming ----------------
// r15/r16/r17: K/V per (b,h) = 512KB, L2-resident; all 16 blocks of a bh land
// on one XCD (bh=bid&31 -> bid%8 = bh%8) -> 4 bh x 512KB = 2MB < 4MB L2/XCD.
// r4/r5 showed flash is per-round latency-bound (lockstep barrier+drain+
// ds_read chain, nothing saturated; halving round count was null). Fix per
// m169 (L2-fit staging is pure overhead): read K (bf16x8) and V^T (bf16x4)
// fragments DIRECTLY from L2 in MFMA layout. No LDS, no barriers, no DMA:
// waves progress independently; 24 outstanding loads/subtile of ILP; all 4
// waves of a block stream the same bytes -> L1 absorbs the re-read.
// (r6/r7 container failures: source audited clean for OOB/align/deadlock;
// resubmitting unchanged. If it fails a 3rd time -> revert flash to r5.)
__global__ __launch_bounds__(256, 2) void flash_attn_kernel(
    const bf16* __restrict__ Qg, const bf16* __restrict__ Kg,
    const bf16* __restrict__ Vtg, bf16* __restrict__ Yg) {
  const int tid = threadIdx.x;
  const int lane = tid & 63, wv = tid >> 6;  // wv in 0..3
  const int quad = lane >> 4, ln = lane & 15;
  const int bid = blockIdx.x;
  const int qt = 15 - (bid >> 5);  // heavy q-tiles first
  const int bh = bid & 31;
  const int bb = bh >> 4, hh = bh & 15;
  const int q0w = qt * 128 + wv * 32;  // this wave's 32 query rows
  const bf16* Qp = Qg + ((size_t)bh * NT + q0w) * ND;
  const bf16* Kbase = Kg + (size_t)bh * NT * ND;
  const bf16* Vtbase = Vtg + (size_t)bh * ND * NT;

  bf16x8 qf[2][2];  // [qb][ks]
#pragma unroll
  for (int qb = 0; qb < 2; ++qb)
#pragma unroll
    for (int ks = 0; ks < 2; ++ks)
      qf[qb][ks] = ld8(Qp + (size_t)(qb * 16 + ln) * ND + ks * 32 + quad * 8);

  f32x4 oacc[2][4] = {};  // [qb][db]; lane=q, quad*4+r = d within db*16
  float li[2] = {0.f, 0.f};

  const int cw = 2 * qt + 1 + (wv >> 1);  // this wave's 64-key subtiles

  for (int ksub = 0; ksub < cw; ++ksub) {
    const int k0 = ksub * 64;
    // Issue ALL loads up-front: K first (QK^T waits only on these, V's
    // latency hides under QK^T + softmax via partial vmcnt waits).
    bf16x8 kfr[2][4];  // [ks][cb]: key=cb*16+ln, d=ks*32+quad*8
#pragma unroll
    for (int ks = 0; ks < 2; ++ks)
#pragma unroll
      for (int cb = 0; cb < 4; ++cb)
        kfr[ks][cb] =
            ld8(Kbase + (size_t)(k0 + cb * 16 + ln) * ND + ks * 32 + quad * 8);
    bf16x4 vfr[4][4];  // [cb][db]: d=db*16+ln, key=k0+cb*16+quad*4
#pragma unroll
    for (int cb = 0; cb < 4; ++cb)
#pragma unroll
      for (int db = 0; db < 4; ++db)
        vfr[cb][db] =
            ld4(Vtbase + (size_t)(db * 16 + ln) * NT + k0 + cb * 16 + quad * 4);

    f32x4 sacc[2][4] = {};  // [qb][cb]; lane=q, quad*4+r = key within cb*16
#pragma unroll
    for (int ks = 0; ks < 2; ++ks)
#pragma unroll
      for (int qb = 0; qb < 2; ++qb)
#pragma unroll
        for (int cb = 0; cb < 4; ++cb)
          sacc[qb][cb] = __builtin_amdgcn_mfma_f32_16x16x32_bf16(
              kfr[ks][cb], qf[qb][ks], sacc[qb][cb], 0, 0, 0);

    if (k0 + 63 > q0w) {  // causal mask on diagonal-crossing tiles
#pragma unroll
      for (int qb = 0; qb < 2; ++qb) {
        int qr = q0w + qb * 16 + ln;
#pragma unroll
        for (int cb = 0; cb < 4; ++cb)
#pragma unroll
          for (int r = 0; r < 4; ++r) {
            int kc = k0 + cb * 16 + quad * 4 + r;
            if (kc > qr) sacc[qb][cb][r] = -1e30f;
          }
      }
    }
    // no-max softmax: P = exp2(S) directly (scale folded into Q)
    bf16x4 pf[2][4];
#pragma unroll
    for (int qb = 0; qb < 2; ++qb) {
      float rs = 0.f;
#pragma unroll
      for (int cb = 0; cb < 4; ++cb) {
        bf16x4 pv;
#pragma unroll
        for (int r = 0; r < 4; ++r) {
          float pexp = EXP2F(sacc[qb][cb][r]);
          rs += pexp;
          pv[r] = (bf16)pexp;
        }
        pf[qb][cb] = pv;
      }
      li[qb] += rs;
    }
    // O^T += V^T·P^T
#pragma unroll
    for (int cb = 0; cb < 4; ++cb)
#pragma unroll
      for (int qb = 0; qb < 2; ++qb)
#pragma unroll
        for (int db = 0; db < 4; ++db)
          oacc[qb][db] = mfma16(vfr[cb][db], pf[qb][cb], oacc[qb][db]);
  }

#pragma unroll
  for (int qb = 0; qb < 2; ++qb) {
    float l = li[qb];
    l += __shfl_xor(l, 16);
    l += __shfl_xor(l, 32);
    float inv = RCPF(l);
    int row = q0w + qb * 16 + ln;
#pragma unroll
    for (int db = 0; db < 4; ++db) {
      bf16x4 ov;
#pragma unroll
      for (int r = 0; r < 4; ++r) ov[r] = (bf16)(oacc[qb][db][r] * inv);
      *(bf16x4*)(Yg + ((size_t)(bb * NT + row)) * NC + hh * 64 + db * 16 +
                 quad * 4) = ov;
    }
  }
}

// ---------------- proj GEMM: 128x64 tiles -> 512 blocks = 2/CU ----------------
__global__ __launch_bounds__(256, 2) void gemm_proj(
    const bf16* __restrict__ A,    // [4096][1024]  (y)
    const bf16* __restrict__ Bt,   // [1024][1024]  (W_proj^T)
    const float* __restrict__ bias,// [1024]
    float* __restrict__ out) {     // [4096][1024]
  const int K = 1024;
  __shared__ bf16 As[128 * 32];
  __shared__ bf16 Bs[64 * 32];
  const int tid = threadIdx.x;
  const int lane = tid & 63, wv = tid >> 6;
  const int quad = lane >> 4, ln = lane & 15;
  const int m0 = blockIdx.x * 128, n0 = blockIdx.y * 64;
  const int wr = wv * 32;
  const int rA = tid >> 2, cA = (tid & 3) * 8;
  f32x4 acc[2][4] = {};

  for (int kt = 0; kt < K / 32; ++kt) {
    const int k0 = kt * 32;
#pragma unroll
    for (int inst = 0; inst < 2; ++inst)
      async16(A + (size_t)(m0 + inst * 64 + rA) * K + k0 + cA,
              &As[inst * 2048 + wv * 512]);
    async16(Bt + (size_t)(n0 + rA) * K + k0 + cA, &Bs[wv * 512]);
    __syncthreads();
    bf16x8 aF[2], bF[4];
#pragma unroll
    for (int i = 0; i < 2; ++i)
      aF[i] = ld8(&As[(wr + i * 16 + ln) * 32 + quad * 8]);
#pragma unroll
    for (int i = 0; i < 4; ++i)
      bF[i] = ld8(&Bs[(i * 16 + ln) * 32 + quad * 8]);
#pragma unroll
    for (int rb = 0; rb < 2; ++rb)
#pragma unroll
      for (int cb = 0; cb < 4; ++cb)
        acc[rb][cb] = __builtin_amdgcn_mfma_f32_16x16x32_bf16(
            aF[rb], bF[cb], acc[rb][cb], 0, 0, 0);
    __syncthreads();
  }
#pragma unroll
  for (int rb = 0; rb < 2; ++rb) {
#pragma unroll
    for (int cb = 0; cb < 4; ++cb) {
      int gn = n0 + cb * 16 + ln;
      float bs = bias[gn];
#pragma unroll
      for (int r = 0; r < 4; ++r) {
        int gm = m0 + wr + rb * 16 + quad * 4 + r;
        out[(size_t)gm * 1024 + gn] = acc[rb][cb][r] + bs;
      }
    }
  }
}

extern "C" void kernel_launch(void* const* d_in, const int* in_sizes, int n_in,
                              void* d_out, int out_size, void* d_ws, size_t ws_size,
                              hipStream_t stream) {
  const float* x      = (const float*)d_in[0];
  const float* W_attn = (const float*)d_in[1];
  const float* b_attn = (const float*)d_in[2];
  const float* W_proj = (const float*)d_in[3];
  const float* b_proj = (const float*)d_in[4];
  float* out = (float*)d_out;

  bf16* ws  = (bf16*)d_ws;
  bf16* xb  = ws;                          // 4096*1024; becomes Y after gemm_qkv
  bf16* Wab = xb + (size_t)4096 * 1024;    // 3072*1024
  bf16* Wpb = Wab + (size_t)3072 * 1024;   // 1024*1024
  bf16* Qb  = Wpb + (size_t)1024 * 1024;   // 32*2048*64
  bf16* Kb  = Qb + (size_t)32 * 2048 * 64;
  bf16* Vtb = Kb + (size_t)32 * 2048 * 64; // [B,H,D,T] written by gemm_qkv
  bf16* Yb  = xb;                          // alias: xb dead after gemm_qkv

  prep<<<2048 + 96 * 32 + 32 * 32, 256, 0, stream>>>(x, xb, W_attn, Wab,
                                                     W_proj, Wpb);
  gemm_qkv<<<dim3(32, 24), 256, 0, stream>>>(xb, Wab, b_attn, Qb, Kb, Vtb);
  flash_attn_kernel<<<512, 256, 0, stream>>>(Qb, Kb, Vtb, Yb);
  gemm_proj<<<dim3(32, 16), 256, 0, stream>>>(Yb, Wpb, b_proj, out);
}

// Round 9
// 164.004 us; speedup vs baseline: 1.5929x; 1.5929x over previous
//
#include <hip/hip_runtime.h>

typedef __bf16 bf16;
typedef __bf16 bf16x4 __attribute__((ext_vector_type(4)));
typedef __bf16 bf16x8 __attribute__((ext_vector_type(8)));
typedef short s16x4 __attribute__((ext_vector_type(4)));
typedef float f32x4 __attribute__((ext_vector_type(4)));
typedef unsigned int u32x4 __attribute__((ext_vector_type(4)));

#define NB 2
#define NT 2048
#define NC 1024
#define NH 16
#define ND 64

#if __has_builtin(__builtin_amdgcn_exp2f)
#define EXP2F(x) __builtin_amdgcn_exp2f(x)
#else
#define EXP2F(x) __expf(0.69314718055994531f * (x))
#endif

#if __has_builtin(__builtin_amdgcn_rcpf)
#define RCPF(x) __builtin_amdgcn_rcpf(x)
#else
#define RCPF(x) (1.0f / (x))
#endif

__device__ __forceinline__ void async16(const void* g, void* l) {
  __builtin_amdgcn_global_load_lds(
      (const __attribute__((address_space(1))) void*)g,
      (__attribute__((address_space(3))) void*)l, 16, 0, 0);
}

__device__ __forceinline__ bf16x8 ld8(const bf16* p) {
  return *reinterpret_cast<const bf16x8*>(p);
}

// 16x16x16 bf16 MFMA: A-frag layout == 16x16 C-layout, so P^T feeds B directly
__device__ __forceinline__ f32x4 mfma16(bf16x4 a, bf16x4 b, f32x4 c) {
  s16x4 ai = __builtin_bit_cast(s16x4, a);
  s16x4 bi = __builtin_bit_cast(s16x4, b);
#if __has_builtin(__builtin_amdgcn_mfma_f32_16x16x16bf16_1k)
  return __builtin_amdgcn_mfma_f32_16x16x16bf16_1k(ai, bi, c, 0, 0, 0);
#else
  f32x4 d;
  asm("v_mfma_f32_16x16x16_bf16 %0, %1, %2, %3"
      : "=v"(d) : "v"(ai), "v"(bi), "v"(c));
  return d;
#endif
}

// ---------------- prep: x->bf16 cvt + both weight transposes, one launch ----------------
__global__ __launch_bounds__(256) void prep(
    const float* __restrict__ x, bf16* __restrict__ xb,
    const float* __restrict__ Wa, bf16* __restrict__ Da,
    const float* __restrict__ Wp, bf16* __restrict__ Dp) {
  int bx = blockIdx.x;
  if (bx < 2048) {
    int i = (bx * 256 + threadIdx.x) * 8;
    const float4* s = (const float4*)(x + i);
    float4 a = s[0], b = s[1];
    bf16x8 o;
    o[0] = (bf16)a.x; o[1] = (bf16)a.y; o[2] = (bf16)a.z; o[3] = (bf16)a.w;
    o[4] = (bf16)b.x; o[5] = (bf16)b.y; o[6] = (bf16)b.z; o[7] = (bf16)b.w;
    *(bf16x8*)(xb + i) = o;
    return;
  }
  __shared__ float tile[32][33];
  int idx = bx - 2048;
  const float* src;
  bf16* dst;
  int Cc, cb, rb;
  if (idx < 96 * 32) { src = Wa; dst = Da; Cc = 3072; cb = idx % 96; rb = idx / 96; }
  else { idx -= 96 * 32; src = Wp; dst = Dp; Cc = 1024; cb = idx % 32; rb = idx / 32; }
  int tx = threadIdx.x & 31, ty = threadIdx.x >> 5;
  int r0 = rb * 32, c0 = cb * 32;
#pragma unroll
  for (int i = 0; i < 4; ++i)
    tile[ty + i * 8][tx] = src[(size_t)(r0 + ty + i * 8) * Cc + c0 + tx];
  __syncthreads();
#pragma unroll
  for (int i = 0; i < 4; ++i)
    dst[(size_t)(c0 + ty + i * 8) * 1024 + r0 + tx] = (bf16)tile[tx][ty + i * 8];
}

// ---------------- QKV GEMM: [4096,1024] x [3072,1024]^T ----------------
// r18: r1 structure + BK=64 as TWO side-by-side 32-col subtiles (As[2][...]).
// Per-subtile staging/fragment/LDS layout byte-identical to r1 (proven m97
// pattern); barrier pairs halved 32->16 (m97: ~20% of time is the per-barrier
// vmcnt(0) drain). LDS 32KB -> still 3 blocks/CU at (256,3).
__global__ __launch_bounds__(256, 3) void gemm_qkv(
    const bf16* __restrict__ A,    // [4096][1024]
    const bf16* __restrict__ Bt,   // [3072][1024]  (W_attn^T)
    const float* __restrict__ bias,// [3072]
    bf16* __restrict__ Qo, bf16* __restrict__ Ko, bf16* __restrict__ Vto) {
  const int K = 1024;
  __shared__ bf16 As[2][128 * 32];
  __shared__ bf16 Bs[2][128 * 32];
  const int tid = threadIdx.x;
  const int lane = tid & 63, wv = tid >> 6;
  const int quad = lane >> 4, ln = lane & 15;
  const int m0 = blockIdx.x * 128, n0 = blockIdx.y * 128;
  const int wr = (wv >> 1) * 64, wc = (wv & 1) * 64;
  const int rA = tid >> 2, cA = (tid & 3) * 8;
  f32x4 acc[4][4] = {};

  for (int kt = 0; kt < K / 64; ++kt) {
    const int k0 = kt * 64;
#pragma unroll
    for (int ss = 0; ss < 2; ++ss) {
#pragma unroll
      for (int inst = 0; inst < 2; ++inst) {
        async16(A + (size_t)(m0 + inst * 64 + rA) * K + k0 + ss * 32 + cA,
                &As[ss][inst * 2048 + wv * 512]);
        async16(Bt + (size_t)(n0 + inst * 64 + rA) * K + k0 + ss * 32 + cA,
                &Bs[ss][inst * 2048 + wv * 512]);
      }
    }
    __syncthreads();
#pragma unroll
    for (int ss = 0; ss < 2; ++ss) {
      bf16x8 aF[4], bF[4];
#pragma unroll
      for (int i = 0; i < 4; ++i) {
        aF[i] = ld8(&As[ss][(wr + i * 16 + ln) * 32 + quad * 8]);
        bF[i] = ld8(&Bs[ss][(wc + i * 16 + ln) * 32 + quad * 8]);
      }
#pragma unroll
      for (int rb = 0; rb < 4; ++rb)
#pragma unroll
        for (int cb = 0; cb < 4; ++cb)
          acc[rb][cb] = __builtin_amdgcn_mfma_f32_16x16x32_bf16(
              aF[rb], bF[cb], acc[rb][cb], 0, 0, 0);
    }
    __syncthreads();
  }
  // epilogue: fold (1/8)*log2(e) into Q (exp2-domain softmax)
#pragma unroll
  for (int rb = 0; rb < 4; ++rb) {
#pragma unroll
    for (int cb = 0; cb < 4; ++cb) {
      int gn = n0 + wc + cb * 16 + ln;
      int part = gn >> 10, c = gn & 1023;
      int h = c >> 6, dd = c & 63;
      float bs = bias[gn];
      int gm0 = m0 + wr + rb * 16 + quad * 4;  // 4 consecutive rows
      int b = gm0 >> 11, t0 = gm0 & 2047;
      if (part == 2) {
        bf16x4 vv;
#pragma unroll
        for (int r = 0; r < 4; ++r) vv[r] = (bf16)(acc[rb][cb][r] + bs);
        *(bf16x4*)(Vto + ((size_t)(b * NH + h) * ND + dd) * NT + t0) = vv;
      } else {
        bf16* dst = part == 0 ? Qo : Ko;
        float sc = part == 0 ? 0.18033688f : 1.0f;  // 0.125 * log2(e)
#pragma unroll
        for (int r = 0; r < 4; ++r)
          dst[((size_t)(b * NH + h) * NT + t0 + r) * ND + dd] =
              (bf16)((acc[rb][cb][r] + bs) * sc);
      }
    }
  }
}

// ---------------- flash attention: KVBLK=128 (r5 exact, best measured) ----------------
// r18: direct-L2 streaming (r8) FALSIFIED: 131us, FETCH 12MB (L2 did serve)
// but MfmaUtil 7.7% -- fragment-layout loads are scattered (16 lines per
// wave-op), request/latency-bound with no LDS broadcast. Coalesced DMA +
// LDS re-read is the right structure; restore r5 (measured best, 167.0).
__global__ __launch_bounds__(256, 2) void flash_attn_kernel(
    const bf16* __restrict__ Qg, const bf16* __restrict__ Kg,
    const bf16* __restrict__ Vtg, bf16* __restrict__ Yg) {
  __shared__ __align__(16) char smem[2][32768];  // [buf][K s0|K s1|V s0|V s1] x 8KB
  const int tid = threadIdx.x;
  const int lane = tid & 63, wv = tid >> 6;  // wv in 0..3
  const int quad = lane >> 4, ln = lane & 15;
  const int bid = blockIdx.x;
  const int qt = 15 - (bid >> 5);  // heavy q-tiles first
  const int bh = bid & 31;
  const int bb = bh >> 4, hh = bh & 15;
  const int q0w = qt * 128 + wv * 32;  // this wave's 32 query rows
  const bf16* Qp = Qg + ((size_t)bh * NT + q0w) * ND;
  const bf16* Kbase = Kg + (size_t)bh * NT * ND;
  const bf16* Vtbase = Vtg + (size_t)bh * ND * NT;

  const int sub = lane >> 3, sch = lane & 7;
  const int swz = ln & 7;

  bf16x8 qf[2][2];  // [qb][ks]
#pragma unroll
  for (int qb = 0; qb < 2; ++qb)
#pragma unroll
    for (int ks = 0; ks < 2; ++ks)
      qf[qb][ks] = ld8(Qp + (size_t)(qb * 16 + ln) * ND + ks * 32 + quad * 8);

  f32x4 oacc[2][4] = {};  // [qb][db]; lane=q, quad*4+r = d within db*16
  float li[2] = {0.f, 0.f};

  const int nt = qt + 1;                  // 128-key tiles staged by block
  const int cw = 2 * qt + 1 + (wv >> 1);  // compute bound in 64-key subtiles

  // Stage one 128-key tile = two r1-style 64-key subtiles (8 async16/thr).
#define STAGE128(KT, P)                                                        \
  {                                                                            \
    int r0s = wv * 16 + sub;                                                   \
    int gch = sch ^ sub;                                                       \
    _Pragma("unroll") for (int s = 0; s < 2; ++s) {                            \
      const int k0s = (KT) * 128 + s * 64;                                     \
      char* Kl = smem[P] + s * 8192;                                           \
      char* Vl = smem[P] + 16384 + s * 8192;                                   \
      async16(Kbase + (size_t)(k0s + r0s) * ND + gch * 8, Kl + wv * 16 * 128); \
      async16(Kbase + (size_t)(k0s + r0s + 8) * ND + gch * 8,                  \
              Kl + wv * 16 * 128 + 1024);                                      \
      async16(Vtbase + (size_t)r0s * NT + k0s + gch * 8, Vl + wv * 16 * 128);  \
      async16(Vtbase + (size_t)(r0s + 8) * NT + k0s + gch * 8,                 \
              Vl + wv * 16 * 128 + 1024);                                      \
    }                                                                          \
  }

  STAGE128(0, 0);
  for (int kt = 0; kt < nt; ++kt) {
    const int p = kt & 1;
    __syncthreads();  // drains DMA for tile kt (issued last round)
    if (kt + 1 < nt) STAGE128(kt + 1, p ^ 1);
#pragma unroll
    for (int s = 0; s < 2; ++s) {
      const int ksub = 2 * kt + s;
      if (ksub < cw) {
        const char* Kl = smem[p] + s * 8192;
        const char* Vl = smem[p] + 16384 + s * 8192;
        const int k0 = ksub * 64;
        f32x4 sacc[2][4] = {};  // [qb][cb]; lane=q, quad*4+r = key in cb*16
#pragma unroll
        for (int ks = 0; ks < 2; ++ks) {
          bf16x8 kfr[4];
#pragma unroll
          for (int cb = 0; cb < 4; ++cb)
            kfr[cb] = *(const bf16x8*)(Kl + (cb * 16 + ln) * 128 +
                                       (((ks * 4 + quad) ^ swz) * 16));
#pragma unroll
          for (int qb = 0; qb < 2; ++qb)
#pragma unroll
            for (int cb = 0; cb < 4; ++cb)
              sacc[qb][cb] = __builtin_amdgcn_mfma_f32_16x16x32_bf16(
                  kfr[cb], qf[qb][ks], sacc[qb][cb], 0, 0, 0);
        }
        if (k0 + 63 > q0w) {  // causal mask on diagonal-crossing tiles
#pragma unroll
          for (int qb = 0; qb < 2; ++qb) {
            int qr = q0w + qb * 16 + ln;
#pragma unroll
            for (int cb = 0; cb < 4; ++cb)
#pragma unroll
              for (int r = 0; r < 4; ++r) {
                int kc = k0 + cb * 16 + quad * 4 + r;
                if (kc > qr) sacc[qb][cb][r] = -1e30f;
              }
          }
        }
        // no-max softmax: P = exp2(S) directly (scale folded into Q)
        bf16x4 pf[2][4];
#pragma unroll
        for (int qb = 0; qb < 2; ++qb) {
          float rs = 0.f;
#pragma unroll
          for (int cb = 0; cb < 4; ++cb) {
            bf16x4 pv;
#pragma unroll
            for (int r = 0; r < 4; ++r) {
              float pexp = EXP2F(sacc[qb][cb][r]);
              rs += pexp;
              pv[r] = (bf16)pexp;
            }
            pf[qb][cb] = pv;
          }
          li[qb] += rs;
        }
        // O^T += V^T·P^T ; vfr loaded once per cb, used by both q-blocks
#pragma unroll
        for (int cb = 0; cb < 4; ++cb) {
          bf16x4 vfr[4];
#pragma unroll
          for (int db = 0; db < 4; ++db)
            vfr[db] = *(const bf16x4*)(Vl + (db * 16 + ln) * 128 +
                                       (((cb * 2 + (quad >> 1)) ^ swz) * 16) +
                                       (quad & 1) * 8);
#pragma unroll
          for (int qb = 0; qb < 2; ++qb)
#pragma unroll
            for (int db = 0; db < 4; ++db)
              oacc[qb][db] = mfma16(vfr[db], pf[qb][cb], oacc[qb][db]);
        }
      }
    }
  }
#undef STAGE128

#pragma unroll
  for (int qb = 0; qb < 2; ++qb) {
    float l = li[qb];
    l += __shfl_xor(l, 16);
    l += __shfl_xor(l, 32);
    float inv = RCPF(l);
    int row = q0w + qb * 16 + ln;
#pragma unroll
    for (int db = 0; db < 4; ++db) {
      bf16x4 ov;
#pragma unroll
      for (int r = 0; r < 4; ++r) ov[r] = (bf16)(oacc[qb][db][r] * inv);
      *(bf16x4*)(Yg + ((size_t)(bb * NT + row)) * NC + hh * 64 + db * 16 +
                 quad * 4) = ov;
    }
  }
}

// ---------------- proj GEMM: 128x64 tiles, BK=64 dual subtiles ----------------
// r18: same BK=64 trick as qkv; barriers halved. LDS 24KB, 2 blocks/CU.
__global__ __launch_bounds__(256, 2) void gemm_proj(
    const bf16* __restrict__ A,    // [4096][1024]  (y)
    const bf16* __restrict__ Bt,   // [1024][1024]  (W_proj^T)
    const float* __restrict__ bias,// [1024]
    float* __restrict__ out) {     // [4096][1024]
  const int K = 1024;
  __shared__ bf16 As[2][128 * 32];
  __shared__ bf16 Bs[2][64 * 32];
  const int tid = threadIdx.x;
  const int lane = tid & 63, wv = tid >> 6;
  const int quad = lane >> 4, ln = lane & 15;
  const int m0 = blockIdx.x * 128, n0 = blockIdx.y * 64;
  const int wr = wv * 32;
  const int rA = tid >> 2, cA = (tid & 3) * 8;
  f32x4 acc[2][4] = {};

  for (int kt = 0; kt < K / 64; ++kt) {
    const int k0 = kt * 64;
#pragma unroll
    for (int ss = 0; ss < 2; ++ss) {
#pragma unroll
      for (int inst = 0; inst < 2; ++inst)
        async16(A + (size_t)(m0 + inst * 64 + rA) * K + k0 + ss * 32 + cA,
                &As[ss][inst * 2048 + wv * 512]);
      async16(Bt + (size_t)(n0 + rA) * K + k0 + ss * 32 + cA, &Bs[ss][wv * 512]);
    }
    __syncthreads();
#pragma unroll
    for (int ss = 0; ss < 2; ++ss) {
      bf16x8 aF[2], bF[4];
#pragma unroll
      for (int i = 0; i < 2; ++i)
        aF[i] = ld8(&As[ss][(wr + i * 16 + ln) * 32 + quad * 8]);
#pragma unroll
      for (int i = 0; i < 4; ++i)
        bF[i] = ld8(&Bs[ss][(i * 16 + ln) * 32 + quad * 8]);
#pragma unroll
      for (int rb = 0; rb < 2; ++rb)
#pragma unroll
        for (int cb = 0; cb < 4; ++cb)
          acc[rb][cb] = __builtin_amdgcn_mfma_f32_16x16x32_bf16(
              aF[rb], bF[cb], acc[rb][cb], 0, 0, 0);
    }
    __syncthreads();
  }
#pragma unroll
  for (int rb = 0; rb < 2; ++rb) {
#pragma unroll
    for (int cb = 0; cb < 4; ++cb) {
      int gn = n0 + cb * 16 + ln;
      float bs = bias[gn];
#pragma unroll
      for (int r = 0; r < 4; ++r) {
        int gm = m0 + wr + rb * 16 + quad * 4 + r;
        out[(size_t)gm * 1024 + gn] = acc[rb][cb][r] + bs;
      }
    }
  }
}

extern "C" void kernel_launch(void* const* d_in, const int* in_sizes, int n_in,
                              void* d_out, int out_size, void* d_ws, size_t ws_size,
                              hipStream_t stream) {
  const float* x      = (const float*)d_in[0];
  const float* W_attn = (const float*)d_in[1];
  const float* b_attn = (const float*)d_in[2];
  const float* W_proj = (const float*)d_in[3];
  const float* b_proj = (const float*)d_in[4];
  float* out = (float*)d_out;

  bf16* ws  = (bf16*)d_ws;
  bf16* xb  = ws;                          // 4096*1024; becomes Y after gemm_qkv
  bf16* Wab = xb + (size_t)4096 * 1024;    // 3072*1024
  bf16* Wpb = Wab + (size_t)3072 * 1024;   // 1024*1024
  bf16* Qb  = Wpb + (size_t)1024 * 1024;   // 32*2048*64
  bf16* Kb  = Qb + (size_t)32 * 2048 * 64;
  bf16* Vtb = Kb + (size_t)32 * 2048 * 64; // [B,H,D,T] written by gemm_qkv
  bf16* Yb  = xb;                          // alias: xb dead after gemm_qkv

  prep<<<2048 + 96 * 32 + 32 * 32, 256, 0, stream>>>(x, xb, W_attn, Wab,
                                                     W_proj, Wpb);
  gemm_qkv<<<dim3(32, 24), 256, 0, stream>>>(xb, Wab, b_attn, Qb, Kb, Vtb);
  flash_attn_kernel<<<512, 256, 0, stream>>>(Qb, Kb, Vtb, Yb);
  gemm_proj<<<dim3(32, 16), 256, 0, stream>>>(Yb, Wpb, b_proj, out);
}